// Round 1
// baseline (205.550 us; speedup 1.0000x reference)
//
#include <hip/hip_runtime.h>

#define M_TOK 1024
#define NOUT  4096
#define KIN   4096

#define BM 128
#define BN 128
#define BK 32
#define NKT (KIN / BK)  // 128 k-tiles

typedef __attribute__((ext_vector_type(8))) short bf16x8_t;
typedef __attribute__((ext_vector_type(4))) float f32x4_t;

// ---- pass 1: binarize weight (fp32 -> bf16 {0,1}) and cast x (fp32 -> bf16 RNE) ----

__device__ __forceinline__ unsigned pack_bf16(float a, float b) {
  unsigned ua = __float_as_uint(a);
  unsigned ub = __float_as_uint(b);
  ua = (ua + 0x7FFFu + ((ua >> 16) & 1u)) >> 16;
  ub = (ub + 0x7FFFu + ((ub >> 16) & 1u)) >> 16;
  return ua | (ub << 16);
}

__global__ __launch_bounds__(256) void prep_kernel(
    const float4* __restrict__ w4, const float4* __restrict__ x4,
    uint2* __restrict__ wb, uint2* __restrict__ xb) {
  const int NW4 = (NOUT * KIN) / 4;   // 4,194,304
  const int NX4 = (M_TOK * KIN) / 4;  // 1,048,576
  const int stride = gridDim.x * blockDim.x;
  for (int i = blockIdx.x * blockDim.x + threadIdx.x; i < NW4 + NX4; i += stride) {
    if (i < NW4) {
      float4 v = w4[i];
      // bf16 1.0 = 0x3F80; pack two per dword
      unsigned lo = (v.x > 0.f ? 0x3F80u : 0u) | (v.y > 0.f ? 0x3F800000u : 0u);
      unsigned hi = (v.z > 0.f ? 0x3F80u : 0u) | (v.w > 0.f ? 0x3F800000u : 0u);
      wb[i] = make_uint2(lo, hi);
    } else {
      int j = i - NW4;
      float4 v = x4[j];
      xb[j] = make_uint2(pack_bf16(v.x, v.y), pack_bf16(v.z, v.w));
    }
  }
}

// ---- pass 2: bf16 MFMA GEMM, C[m][n] = sum_k A[m][k] * B[n][k], epilogue *= s_eff[n] ----
// A = Xb [1024][4096] bf16 (K-major), B = Wb [4096][4096] bf16 (K-major, i.e. B^T form).
// 128x128 block tile, 4 waves 2x2, each wave 64x64 (4x4 MFMA 16x16x32 tiles).
// Single-barrier double-buffered K-loop: stage(k+1) issued AFTER the barrier so the
// barrier's vmcnt(0) drain only waits on the stage from the previous iteration.

__global__ __launch_bounds__(256) void gemm_bin_kernel(
    const unsigned short* __restrict__ A,
    const unsigned short* __restrict__ B,
    const float* __restrict__ sf,
    float* __restrict__ C) {
  __shared__ unsigned short As[2][BM * BK];
  __shared__ unsigned short Bs[2][BN * BK];

  const int tid  = threadIdx.x;
  const int lane = tid & 63;
  const int wave = tid >> 6;
  const int wm   = (wave >> 1) * 64;  // wave row offset in tile
  const int wn   = (wave & 1) * 64;   // wave col offset in tile
  const int quad = lane >> 4;
  const int l16  = lane & 15;
  const int m0   = blockIdx.y * BM;
  const int n0   = blockIdx.x * BN;

  f32x4_t acc[4][4];
#pragma unroll
  for (int i = 0; i < 4; ++i)
#pragma unroll
    for (int j = 0; j < 4; ++j)
      acc[i][j] = (f32x4_t){0.f, 0.f, 0.f, 0.f};

  // staging: each tile = 512 x 16B chunks; this thread owns chunks c0=tid, c1=tid+256.
  // chunk c -> row (c>>2), k-offset (c&3)*8. LDS dest = base + c*16B, which per wave is
  // wave-uniform base + lane*16 (global_load_lds requirement).
  const int c0 = tid, c1 = tid + 256;
  const int r0 = c0 >> 2, ko0 = (c0 & 3) * 8;
  const int r1 = c1 >> 2, ko1 = (c1 & 3) * 8;

  const unsigned short* gA0 = A + (size_t)(m0 + r0) * KIN + ko0;
  const unsigned short* gA1 = A + (size_t)(m0 + r1) * KIN + ko1;
  const unsigned short* gB0 = B + (size_t)(n0 + r0) * KIN + ko0;
  const unsigned short* gB1 = B + (size_t)(n0 + r1) * KIN + ko1;

#define STAGE(buf, koff)                                                                   \
  do {                                                                                     \
    __builtin_amdgcn_global_load_lds(                                                      \
        (const __attribute__((address_space(1))) void*)(gA0 + (koff)),                     \
        (__attribute__((address_space(3))) void*)&As[(buf)][c0 * 8], 16, 0, 0);            \
    __builtin_amdgcn_global_load_lds(                                                      \
        (const __attribute__((address_space(1))) void*)(gA1 + (koff)),                     \
        (__attribute__((address_space(3))) void*)&As[(buf)][c1 * 8], 16, 0, 0);            \
    __builtin_amdgcn_global_load_lds(                                                      \
        (const __attribute__((address_space(1))) void*)(gB0 + (koff)),                     \
        (__attribute__((address_space(3))) void*)&Bs[(buf)][c0 * 8], 16, 0, 0);            \
    __builtin_amdgcn_global_load_lds(                                                      \
        (const __attribute__((address_space(1))) void*)(gB1 + (koff)),                     \
        (__attribute__((address_space(3))) void*)&Bs[(buf)][c1 * 8], 16, 0, 0);            \
  } while (0)

  STAGE(0, 0);

  for (int kt = 0; kt < NKT; ++kt) {
    __syncthreads();  // drains prev stage (vmcnt(0)) + protects buffer reuse
    const int cur = kt & 1;
    if (kt + 1 < NKT) {
      STAGE(1 - cur, (size_t)(kt + 1) * BK);
    }
    bf16x8_t af[4], bfr[4];
#pragma unroll
    for (int i = 0; i < 4; ++i) {
      af[i]  = *(const bf16x8_t*)&As[cur][(wm + i * 16 + l16) * BK + quad * 8];
      bfr[i] = *(const bf16x8_t*)&Bs[cur][(wn + i * 16 + l16) * BK + quad * 8];
    }
#pragma unroll
    for (int i = 0; i < 4; ++i)
#pragma unroll
      for (int j = 0; j < 4; ++j)
        acc[i][j] = __builtin_amdgcn_mfma_f32_16x16x32_bf16(af[i], bfr[j], acc[i][j], 0, 0, 0);
  }

  // epilogue: C/D layout col = lane&15, row = quad*4 + reg
#pragma unroll
  for (int j = 0; j < 4; ++j) {
    const int n = n0 + wn + j * 16 + l16;
    const float s = rintf(fmaxf(sf[n], 1.0f));  // round(clamp(s,1)) fwd value, RNE like jnp.round
#pragma unroll
    for (int i = 0; i < 4; ++i) {
      const int mrow = m0 + wm + i * 16 + quad * 4;
#pragma unroll
      for (int r = 0; r < 4; ++r)
        C[(size_t)(mrow + r) * NOUT + n] = acc[i][j][r] * s;
    }
  }
#undef STAGE
}

extern "C" void kernel_launch(void* const* d_in, const int* in_sizes, int n_in,
                              void* d_out, int out_size, void* d_ws, size_t ws_size,
                              hipStream_t stream) {
  const float* x  = (const float*)d_in[0];  // [1024][4096]
  const float* w  = (const float*)d_in[1];  // [4096][4096]
  const float* sf = (const float*)d_in[2];  // [4096]
  float* out = (float*)d_out;               // [1024][4096]

  unsigned short* Wb = (unsigned short*)d_ws;                                  // 32 MB
  unsigned short* Xb = (unsigned short*)((char*)d_ws + (size_t)NOUT * KIN * 2); // 8 MB

  prep_kernel<<<4096, 256, 0, stream>>>((const float4*)w, (const float4*)x,
                                        (uint2*)Wb, (uint2*)Xb);

  dim3 grid(NOUT / BN, M_TOK / BM);  // 32 x 8 = 256 blocks
  gemm_bin_kernel<<<grid, 256, 0, stream>>>(Xb, Wb, sf, out);
}

// Round 2
// 204.010 us; speedup vs baseline: 1.0075x; 1.0075x over previous
//
#include <hip/hip_runtime.h>

#define M_TOK 1024
#define NOUT  4096
#define KIN   4096

#define BM 128
#define BN 128
#define BK 32
#define KSPLIT 4
#define KPER (KIN / KSPLIT)   // 1024
#define NKT  (KPER / BK)      // 32 k-tiles per block

typedef __attribute__((ext_vector_type(8))) short bf16x8_t;
typedef __attribute__((ext_vector_type(4))) float f32x4_t;

// ---- prep: binarize w (fp32 -> bf16 {0,1}), cast x (fp32 -> bf16 RNE); 8 elems/thread ----

__device__ __forceinline__ unsigned pack_bf16(float a, float b) {
  unsigned ua = __float_as_uint(a);
  unsigned ub = __float_as_uint(b);
  ua = (ua + 0x7FFFu + ((ua >> 16) & 1u)) >> 16;
  ub = (ub + 0x7FFFu + ((ub >> 16) & 1u)) >> 16;
  return ua | (ub << 16);
}

__global__ __launch_bounds__(256) void prep_w(const float4* __restrict__ w4,
                                              uint4* __restrict__ wb) {
  int t = blockIdx.x * 256 + threadIdx.x;
  float4 a = w4[2 * t], b = w4[2 * t + 1];
  uint4 o;
  o.x = (a.x > 0.f ? 0x3F80u : 0u) | (a.y > 0.f ? 0x3F800000u : 0u);
  o.y = (a.z > 0.f ? 0x3F80u : 0u) | (a.w > 0.f ? 0x3F800000u : 0u);
  o.z = (b.x > 0.f ? 0x3F80u : 0u) | (b.y > 0.f ? 0x3F800000u : 0u);
  o.w = (b.z > 0.f ? 0x3F80u : 0u) | (b.w > 0.f ? 0x3F800000u : 0u);
  wb[t] = o;
}

__global__ __launch_bounds__(256) void prep_x(const float4* __restrict__ x4,
                                              uint4* __restrict__ xb) {
  int t = blockIdx.x * 256 + threadIdx.x;
  float4 a = x4[2 * t], b = x4[2 * t + 1];
  uint4 o;
  o.x = pack_bf16(a.x, a.y);
  o.y = pack_bf16(a.z, a.w);
  o.z = pack_bf16(b.x, b.y);
  o.w = pack_bf16(b.z, b.w);
  xb[t] = o;
}

// ---- GEMM: C[m][n] += sum_k A[m][k]*B[n][k] * s[n], split-K=4 via atomicAdd ----
// Register double-buffer staging (no global_load_lds -> no vmcnt(0) drain at barrier).
// LDS 16B-chunk swizzle: column c stored at (c + (row>>1)) & 3 -> conflict-free reads+writes.

__global__ __launch_bounds__(256, 4) void gemm_bin_kernel(
    const unsigned short* __restrict__ A,
    const unsigned short* __restrict__ B,
    const float* __restrict__ sf,
    float* __restrict__ C) {
  __shared__ unsigned short As[2][BM * BK];  // 8 KB each buf
  __shared__ unsigned short Bs[2][BN * BK];

  const int tid  = threadIdx.x;
  const int lane = tid & 63;
  const int wave = tid >> 6;
  const int wm   = (wave >> 1) * 64;
  const int wn   = (wave & 1) * 64;
  const int quad = lane >> 4;
  const int l16  = lane & 15;
  const int m0   = blockIdx.y * BM;
  const int n0   = blockIdx.x * BN;
  const int kb   = blockIdx.z * KPER;

  // staging: thread owns rows rA and rA+64 of both tiles, 16B chunk kc
  const int rA = tid >> 2, kc = tid & 3;
  const unsigned short* gA0 = A + (size_t)(m0 + rA) * KIN + kb + kc * 8;
  const unsigned short* gA1 = gA0 + (size_t)64 * KIN;
  const unsigned short* gB0 = B + (size_t)(n0 + rA) * KIN + kb + kc * 8;
  const unsigned short* gB1 = gB0 + (size_t)64 * KIN;
  const int colW = (kc + (rA >> 1)) & 3;          // swizzled chunk column
  const int wo0  = rA * BK + colW * 8;            // element offsets in LDS
  const int wo1  = wo0 + 64 * BK;                 // (rA+64)>>1 adds 32 ≡ 0 (mod 4)

  f32x4_t acc[4][4];
#pragma unroll
  for (int i = 0; i < 4; ++i)
#pragma unroll
    for (int j = 0; j < 4; ++j)
      acc[i][j] = (f32x4_t){0.f, 0.f, 0.f, 0.f};

  // prologue: load kt=0 into registers
  uint4 sa0 = *(const uint4*)gA0;
  uint4 sa1 = *(const uint4*)gA1;
  uint4 sb0 = *(const uint4*)gB0;
  uint4 sb1 = *(const uint4*)gB1;

  for (int kt = 0; kt < NKT; ++kt) {
    const int cur = kt & 1;
    // commit staged registers to LDS (compiler inserts the vmcnt wait here,
    // one full compute-phase after the loads were issued)
    *(uint4*)&As[cur][wo0] = sa0;
    *(uint4*)&As[cur][wo1] = sa1;
    *(uint4*)&Bs[cur][wo0] = sb0;
    *(uint4*)&Bs[cur][wo1] = sb1;
    __syncthreads();
    if (kt + 1 < NKT) {
      const int off = (kt + 1) * BK;
      sa0 = *(const uint4*)(gA0 + off);
      sa1 = *(const uint4*)(gA1 + off);
      sb0 = *(const uint4*)(gB0 + off);
      sb1 = *(const uint4*)(gB1 + off);
    }
    bf16x8_t af[4], bfr[4];
#pragma unroll
    for (int i = 0; i < 4; ++i) {
      const int ra = wm + i * 16 + l16;
      af[i] = *(const bf16x8_t*)&As[cur][ra * BK + ((quad + (ra >> 1)) & 3) * 8];
      const int rb = wn + i * 16 + l16;
      bfr[i] = *(const bf16x8_t*)&Bs[cur][rb * BK + ((quad + (rb >> 1)) & 3) * 8];
    }
#pragma unroll
    for (int i = 0; i < 4; ++i)
#pragma unroll
      for (int j = 0; j < 4; ++j)
        acc[i][j] = __builtin_amdgcn_mfma_f32_16x16x32_bf16(af[i], bfr[j], acc[i][j], 0, 0, 0);
  }

  // epilogue: C/D layout col = lane&15, row = quad*4 + reg; scale then atomic-accumulate
#pragma unroll
  for (int j = 0; j < 4; ++j) {
    const int n = n0 + wn + j * 16 + l16;
    const float s = rintf(fmaxf(sf[n], 1.0f));
#pragma unroll
    for (int i = 0; i < 4; ++i) {
      const int mrow = m0 + wm + i * 16 + quad * 4;
#pragma unroll
      for (int r = 0; r < 4; ++r)
        atomicAdd(&C[(size_t)(mrow + r) * NOUT + n], acc[i][j][r] * s);
    }
  }
}

extern "C" void kernel_launch(void* const* d_in, const int* in_sizes, int n_in,
                              void* d_out, int out_size, void* d_ws, size_t ws_size,
                              hipStream_t stream) {
  const float* x  = (const float*)d_in[0];  // [1024][4096]
  const float* w  = (const float*)d_in[1];  // [4096][4096]
  const float* sf = (const float*)d_in[2];  // [4096]
  float* out = (float*)d_out;               // [1024][4096]

  unsigned short* Wb = (unsigned short*)d_ws;                                   // 32 MB
  unsigned short* Xb = (unsigned short*)((char*)d_ws + (size_t)NOUT * KIN * 2); // 8 MB

  hipMemsetAsync(d_out, 0, (size_t)M_TOK * NOUT * sizeof(float), stream);
  prep_w<<<8192, 256, 0, stream>>>((const float4*)w, (uint4*)Wb);
  prep_x<<<2048, 256, 0, stream>>>((const float4*)x, (uint4*)Xb);

  dim3 grid(NOUT / BN, M_TOK / BM, KSPLIT);  // 32 x 8 x 4 = 1024 blocks
  gemm_bin_kernel<<<grid, 256, 0, stream>>>(Xb, Wb, sf, out);
}

// Round 3
// 181.979 us; speedup vs baseline: 1.1295x; 1.1211x over previous
//
#include <hip/hip_runtime.h>

#define M_TOK 1024
#define NOUT  4096
#define KIN   4096
#define KBYTES (KIN / 8)   // 512 bitmask bytes per output row

#define BM 128
#define BN 128
#define BK 32
#define NKT (KIN / BK)     // 128 k-tiles

typedef __attribute__((ext_vector_type(8))) short bf16x8_t;
typedef __attribute__((ext_vector_type(4))) float f32x4_t;

// ---- prep_w: w fp32 -> 1-bit mask (bit=1 iff w>0); 32 elems -> 1 dword/thread ----
__global__ __launch_bounds__(256) void prep_w(const float4* __restrict__ w4,
                                              unsigned* __restrict__ wbits) {
  const size_t t = blockIdx.x * 256 + threadIdx.x;
  unsigned b = 0;
#pragma unroll
  for (int q = 0; q < 8; ++q) {
    float4 v = w4[8 * t + q];
    b |= (v.x > 0.f ? 1u : 0u) << (4 * q);
    b |= (v.y > 0.f ? 2u : 0u) << (4 * q);
    b |= (v.z > 0.f ? 4u : 0u) << (4 * q);
    b |= (v.w > 0.f ? 8u : 0u) << (4 * q);
  }
  wbits[t] = b;
}

// ---- prep_x: x fp32 -> bf16 RNE; 8 elems/thread ----
__device__ __forceinline__ unsigned pack_bf16(float a, float b) {
  unsigned ua = __float_as_uint(a);
  unsigned ub = __float_as_uint(b);
  ua = (ua + 0x7FFFu + ((ua >> 16) & 1u)) >> 16;
  ub = (ub + 0x7FFFu + ((ub >> 16) & 1u)) >> 16;
  return ua | (ub << 16);
}

__global__ __launch_bounds__(256) void prep_x(const float4* __restrict__ x4,
                                              uint4* __restrict__ xb) {
  const size_t t = blockIdx.x * 256 + threadIdx.x;
  float4 a = x4[2 * t], b = x4[2 * t + 1];
  uint4 o;
  o.x = pack_bf16(a.x, a.y);
  o.y = pack_bf16(a.z, a.w);
  o.z = pack_bf16(b.x, b.y);
  o.w = pack_bf16(b.z, b.w);
  xb[t] = o;
}

// ---- GEMM: C[m][n] = (sum_k A[m][k]*Wbit[n][k]) * s[n]; no split-K, direct stores ----
// 512 threads = 8 waves (2m x 4n), each wave 64x32 (4x2 MFMA 16x16x32 tiles).
// Register double-buffer staging; R2's measured-conflict-free LDS chunk swizzle.
// B staged from 1-bit mask, expanded to bf16 {0,1} in VALU before ds_write.
__global__ __launch_bounds__(512, 2) void gemm_bin_kernel(
    const unsigned short* __restrict__ A,     // Xb bf16 [1024][4096]
    const unsigned char* __restrict__ Wb,     // bitmask [4096][512] bytes
    const float* __restrict__ sf,
    float* __restrict__ C) {
  __shared__ unsigned short As[2][BM * BK];   // 8 KB per buf
  __shared__ unsigned short Bs[2][BN * BK];

  const int tid  = threadIdx.x;
  const int lane = tid & 63;
  const int wave = tid >> 6;          // 0..7
  const int wm   = (wave >> 2) * 64;  // 0 / 64
  const int wn   = (wave & 3) * 32;   // 0,32,64,96
  const int quad = lane >> 4;
  const int l16  = lane & 15;
  const int m0   = blockIdx.y * BM;
  const int n0   = blockIdx.x * BN;

  // staging: thread owns one 16B chunk of A-tile and one 8-elem chunk of B-tile
  const int row = tid >> 2;           // 0..127
  const int kc  = tid & 3;            // chunk column
  const unsigned short* gA = A + (size_t)(m0 + row) * KIN + kc * 8;
  const unsigned char*  gB = Wb + (size_t)(n0 + row) * KBYTES + kc;
  const int wo = row * BK + ((kc + (row >> 1)) & 3) * 8;  // swizzled LDS offset (elems)

  f32x4_t acc[4][2];
#pragma unroll
  for (int i = 0; i < 4; ++i)
#pragma unroll
    for (int j = 0; j < 2; ++j)
      acc[i][j] = (f32x4_t){0.f, 0.f, 0.f, 0.f};

  // prologue loads for kt=0
  uint4 sa = *(const uint4*)gA;
  unsigned char bby = gB[0];

  for (int kt = 0; kt < NKT; ++kt) {
    const int cur = kt & 1;
    // expand 8 bits -> 8 bf16 {0,1} (4 dwords)
    uint4 bx;
    bx.x = (bby & 1u   ? 0x3F80u : 0u) | (bby & 2u   ? 0x3F800000u : 0u);
    bx.y = (bby & 4u   ? 0x3F80u : 0u) | (bby & 8u   ? 0x3F800000u : 0u);
    bx.z = (bby & 16u  ? 0x3F80u : 0u) | (bby & 32u  ? 0x3F800000u : 0u);
    bx.w = (bby & 64u  ? 0x3F80u : 0u) | (bby & 128u ? 0x3F800000u : 0u);
    *(uint4*)&As[cur][wo] = sa;
    *(uint4*)&Bs[cur][wo] = bx;
    __syncthreads();
    if (kt + 1 < NKT) {
      sa  = *(const uint4*)(gA + (kt + 1) * BK);
      bby = gB[(kt + 1) * 4];
    }
    bf16x8_t af[4], bf2[2];
#pragma unroll
    for (int i = 0; i < 4; ++i) {
      const int ra = wm + i * 16 + l16;
      af[i] = *(const bf16x8_t*)&As[cur][ra * BK + ((quad + (ra >> 1)) & 3) * 8];
    }
#pragma unroll
    for (int j = 0; j < 2; ++j) {
      const int rb = wn + j * 16 + l16;
      bf2[j] = *(const bf16x8_t*)&Bs[cur][rb * BK + ((quad + (rb >> 1)) & 3) * 8];
    }
#pragma unroll
    for (int i = 0; i < 4; ++i)
#pragma unroll
      for (int j = 0; j < 2; ++j)
        acc[i][j] = __builtin_amdgcn_mfma_f32_16x16x32_bf16(af[i], bf2[j], acc[i][j], 0, 0, 0);
  }

  // epilogue: C/D layout col = lane&15, row = quad*4 + reg; direct stores
#pragma unroll
  for (int j = 0; j < 2; ++j) {
    const int n = n0 + wn + j * 16 + l16;
    const float s = rintf(fmaxf(sf[n], 1.0f));
#pragma unroll
    for (int i = 0; i < 4; ++i) {
      const int mr = m0 + wm + i * 16 + quad * 4;
#pragma unroll
      for (int r = 0; r < 4; ++r)
        C[(size_t)(mr + r) * NOUT + n] = acc[i][j][r] * s;
    }
  }
}

extern "C" void kernel_launch(void* const* d_in, const int* in_sizes, int n_in,
                              void* d_out, int out_size, void* d_ws, size_t ws_size,
                              hipStream_t stream) {
  const float* x  = (const float*)d_in[0];  // [1024][4096]
  const float* w  = (const float*)d_in[1];  // [4096][4096]
  const float* sf = (const float*)d_in[2];  // [4096]
  float* out = (float*)d_out;               // [1024][4096]

  unsigned char*  Wbits = (unsigned char*)d_ws;                          // 2 MB
  unsigned short* Xb    = (unsigned short*)((char*)d_ws + (1u << 21));   // 8 MB

  prep_w<<<2048, 256, 0, stream>>>((const float4*)w, (unsigned*)Wbits);
  prep_x<<<2048, 256, 0, stream>>>((const float4*)x, (uint4*)Xb);

  dim3 grid(NOUT / BN, M_TOK / BM);  // 32 x 8 = 256 blocks, 512 threads
  gemm_bin_kernel<<<grid, 512, 0, stream>>>(Xb, Wbits, sf, out);
}

// Round 4
// 171.683 us; speedup vs baseline: 1.1973x; 1.0600x over previous
//
#include <hip/hip_runtime.h>

#define M_TOK 1024
#define NOUT  4096
#define KIN   4096
#define KBYTES (KIN / 8)   // 512 bitmask bytes per output row

#define BM 128
#define BN 128
#define BK 64
#define NKT (KIN / BK)     // 64 k-tiles

typedef __attribute__((ext_vector_type(8))) short bf16x8_t;
typedef __attribute__((ext_vector_type(4))) float f32x4_t;

// ---- prep_w: fp32 -> 1-bit mask via wave ballot; unit-stride reads, coalesced u64 stores ----
// One wave per weight row. Iter q: lane reads w[row*4096 + q*64 + lane] (unit stride);
// ballot(v>0) = 64-bit mask for elements [q*64, q*64+64); lane q keeps it; lane L stores
// its u64 at row*512 + L*8.
__global__ __launch_bounds__(256) void prep_w(const float* __restrict__ w,
                                              unsigned long long* __restrict__ wbits) {
  const int lane = threadIdx.x & 63;
  const int row  = blockIdx.x * 4 + (threadIdx.x >> 6);
  const float* wr = w + (size_t)row * KIN;
  unsigned long long mine = 0;
#pragma unroll 16
  for (int q = 0; q < 64; ++q) {
    float v = wr[q * 64 + lane];
    unsigned long long m = __ballot(v > 0.f);
    if (lane == q) mine = m;
  }
  wbits[(size_t)row * 64 + lane] = mine;
}

// ---- prep_x: fp32 -> bf16 RNE; one unit-stride float4 per thread ----
__device__ __forceinline__ unsigned pack_bf16(float a, float b) {
  unsigned ua = __float_as_uint(a);
  unsigned ub = __float_as_uint(b);
  ua = (ua + 0x7FFFu + ((ua >> 16) & 1u)) >> 16;
  ub = (ub + 0x7FFFu + ((ub >> 16) & 1u)) >> 16;
  return ua | (ub << 16);
}

__global__ __launch_bounds__(256) void prep_x(const float4* __restrict__ x4,
                                              uint2* __restrict__ xb) {
  const size_t t = blockIdx.x * 256 + threadIdx.x;
  float4 v = x4[t];
  xb[t] = make_uint2(pack_bf16(v.x, v.y), pack_bf16(v.z, v.w));
}

// ---- GEMM: C[m][n] = (sum_k A[m][k]*Wbit[n][k]) * s[n] ----
// 512 threads = 8 waves (2m x 4n), wave tile 64x32. BK=64 (64 barriers).
// Register double-buffer staging; LDS chunk swizzle chunk'=(chunk+row)&7
// (reads: 16 rows x same chunk -> each bankgroup hit 2x = free; writes: uniform 8 = b128 min).
__global__ __launch_bounds__(512, 2) void gemm_bin_kernel(
    const unsigned short* __restrict__ A,     // Xb bf16 [1024][4096]
    const unsigned char* __restrict__ Wb,     // bitmask [4096][512] bytes
    const float* __restrict__ sf,
    float* __restrict__ C) {
  __shared__ __align__(16) unsigned short As[2][BM * BK];  // 16 KB per buf
  __shared__ __align__(16) unsigned short Bs[2][BN * BK];

  const int tid  = threadIdx.x;
  const int lane = tid & 63;
  const int wave = tid >> 6;          // 0..7
  const int wm   = (wave >> 2) * 64;  // 0 / 64
  const int wn   = (wave & 3) * 32;   // 0,32,64,96
  const int quad = lane >> 4;
  const int l16  = lane & 15;
  const int m0   = blockIdx.y * BM;
  const int n0   = blockIdx.x * BN;

  // staging: thread owns row r, 32B of A (chunks 2j,2j+1) and 2 bytes of B bits
  const int r  = tid >> 2;            // 0..127
  const int j2 = tid & 3;             // chunk-pair index
  const unsigned short* gA = A + (size_t)(m0 + r) * KIN + j2 * 16;
  const unsigned char*  gB = Wb + (size_t)(n0 + r) * KBYTES + j2 * 2;
  const int cw0 = ((2 * j2 + 0 + r) & 7);   // swizzled chunk positions
  const int cw1 = ((2 * j2 + 1 + r) & 7);
  const int woA0 = r * BK + cw0 * 8, woA1 = r * BK + cw1 * 8;

  f32x4_t acc[4][2];
#pragma unroll
  for (int i = 0; i < 4; ++i)
#pragma unroll
    for (int j = 0; j < 2; ++j)
      acc[i][j] = (f32x4_t){0.f, 0.f, 0.f, 0.f};

  // prologue loads for kt=0
  uint4 sa0 = *(const uint4*)gA;
  uint4 sa1 = *(const uint4*)(gA + 8);
  unsigned short sb = *(const unsigned short*)gB;

  for (int kt = 0; kt < NKT; ++kt) {
    const int cur = kt & 1;
    // expand 16 bits -> 16 bf16 {0,1} (two uint4 chunks)
    uint4 bx0, bx1;
    bx0.x = (sb & 0x1u    ? 0x3F80u : 0u) | (sb & 0x2u    ? 0x3F800000u : 0u);
    bx0.y = (sb & 0x4u    ? 0x3F80u : 0u) | (sb & 0x8u    ? 0x3F800000u : 0u);
    bx0.z = (sb & 0x10u   ? 0x3F80u : 0u) | (sb & 0x20u   ? 0x3F800000u : 0u);
    bx0.w = (sb & 0x40u   ? 0x3F80u : 0u) | (sb & 0x80u   ? 0x3F800000u : 0u);
    bx1.x = (sb & 0x100u  ? 0x3F80u : 0u) | (sb & 0x200u  ? 0x3F800000u : 0u);
    bx1.y = (sb & 0x400u  ? 0x3F80u : 0u) | (sb & 0x800u  ? 0x3F800000u : 0u);
    bx1.z = (sb & 0x1000u ? 0x3F80u : 0u) | (sb & 0x2000u ? 0x3F800000u : 0u);
    bx1.w = (sb & 0x4000u ? 0x3F80u : 0u) | (sb & 0x8000u ? 0x3F800000u : 0u);
    *(uint4*)&As[cur][woA0] = sa0;
    *(uint4*)&As[cur][woA1] = sa1;
    *(uint4*)&Bs[cur][woA0] = bx0;
    *(uint4*)&Bs[cur][woA1] = bx1;
    __syncthreads();
    if (kt + 1 < NKT) {
      const int off = (kt + 1) * BK;
      sa0 = *(const uint4*)(gA + off);
      sa1 = *(const uint4*)(gA + off + 8);
      sb  = *(const unsigned short*)(gB + (kt + 1) * 8);
    }
    bf16x8_t af[2][4], bfr[2][2];
#pragma unroll
    for (int ks = 0; ks < 2; ++ks) {
#pragma unroll
      for (int i = 0; i < 4; ++i) {
        const int ra = wm + i * 16 + l16;
        af[ks][i] = *(const bf16x8_t*)&As[cur][ra * BK + ((ks * 4 + quad + ra) & 7) * 8];
      }
#pragma unroll
      for (int j = 0; j < 2; ++j) {
        const int rb = wn + j * 16 + l16;
        bfr[ks][j] = *(const bf16x8_t*)&Bs[cur][rb * BK + ((ks * 4 + quad + rb) & 7) * 8];
      }
    }
#pragma unroll
    for (int ks = 0; ks < 2; ++ks)
#pragma unroll
      for (int i = 0; i < 4; ++i)
#pragma unroll
        for (int j = 0; j < 2; ++j)
          acc[i][j] = __builtin_amdgcn_mfma_f32_16x16x32_bf16(af[ks][i], bfr[ks][j],
                                                              acc[i][j], 0, 0, 0);
  }

  // epilogue: C/D layout col = lane&15, row = quad*4 + reg
#pragma unroll
  for (int j = 0; j < 2; ++j) {
    const int n = n0 + wn + j * 16 + l16;
    const float s = rintf(fmaxf(sf[n], 1.0f));
#pragma unroll
    for (int i = 0; i < 4; ++i) {
      const int mr = m0 + wm + i * 16 + quad * 4;
#pragma unroll
      for (int rr = 0; rr < 4; ++rr)
        C[(size_t)(mr + rr) * NOUT + n] = acc[i][j][rr] * s;
    }
  }
}

extern "C" void kernel_launch(void* const* d_in, const int* in_sizes, int n_in,
                              void* d_out, int out_size, void* d_ws, size_t ws_size,
                              hipStream_t stream) {
  const float* x  = (const float*)d_in[0];  // [1024][4096]
  const float* w  = (const float*)d_in[1];  // [4096][4096]
  const float* sf = (const float*)d_in[2];  // [4096]
  float* out = (float*)d_out;               // [1024][4096]

  unsigned char*  Wbits = (unsigned char*)d_ws;                          // 2 MB
  unsigned short* Xb    = (unsigned short*)((char*)d_ws + (1u << 21));   // 8 MB

  prep_w<<<1024, 256, 0, stream>>>(w, (unsigned long long*)Wbits);
  prep_x<<<4096, 256, 0, stream>>>((const float4*)x, (uint2*)Xb);

  dim3 grid(NOUT / BN, M_TOK / BM);  // 32 x 8 = 256 blocks, 512 threads
  gemm_bin_kernel<<<grid, 512, 0, stream>>>(Xb, Wbits, sf, out);
}

// Round 5
// 154.396 us; speedup vs baseline: 1.3313x; 1.1120x over previous
//
#include <hip/hip_runtime.h>

#define M_TOK 1024
#define NOUT  4096
#define KIN   4096

typedef __attribute__((ext_vector_type(8))) short bf16x8_t;
typedef __attribute__((ext_vector_type(4))) float f32x4_t;

// workspace layout:
//   Bfrag  2 MB @ 0        (bit-bytes in MFMA B-frag order)
//   Wbits  2 MB @ 2 MB     (row-major u64 bitmask, intermediate)
//   Xfrag  8 MB @ 4 MB     (bf16 x in MFMA A-frag order)

// ---- prep_w: fp32 -> 1-bit mask via wave ballot (coalesced; known-good from R4) ----
__global__ __launch_bounds__(256) void prep_w(const float* __restrict__ w,
                                              unsigned long long* __restrict__ wbits) {
  const int lane = threadIdx.x & 63;
  const int row  = blockIdx.x * 4 + (threadIdx.x >> 6);
  const float* wr = w + (size_t)row * KIN;
  unsigned long long mine = 0;
#pragma unroll 16
  for (int q = 0; q < 64; ++q) {
    float v = wr[q * 64 + lane];
    unsigned long long m = __ballot(v > 0.f);
    if (lane == q) mine = m;
  }
  wbits[(size_t)row * 64 + lane] = mine;
}

// ---- prep_w2: shuffle bits to B-frag byte order ----
// out ushort index t: l = t&63, kt = (t>>6)&63, n16 = t>>12
// value: bytes (0*4+quad) and (1*4+quad) of Wbits[n16*16 + (l&15)][kt]  (quad = l>>4)
__global__ __launch_bounds__(256) void prep_w2(const unsigned long long* __restrict__ wbits,
                                               unsigned short* __restrict__ bfrag) {
  const unsigned t = blockIdx.x * 256 + threadIdx.x;  // 1,048,576 total
  const int l = t & 63, kt = (t >> 6) & 63, n16 = t >> 12;
  const int row = n16 * 16 + (l & 15), quad = l >> 4;
  unsigned long long w64 = wbits[(size_t)row * 64 + kt];
  unsigned b0 = (unsigned)(w64 >> (quad * 8)) & 0xFFu;
  unsigned b1 = (unsigned)(w64 >> (quad * 8 + 32)) & 0xFFu;
  bfrag[t] = (unsigned short)(b0 | (b1 << 8));
}

// ---- prep_x: fp32 -> bf16 RNE, rearranged to A-frag order ----
// out uint4 index t: l = t&63, f = t>>6 = m16*128 + k32
// lane's 16 B = x[m16*16 + (l&15)][k32*32 + (l>>4)*8 .. +8) as bf16
__device__ __forceinline__ unsigned pack_bf16(float a, float b) {
  unsigned ua = __float_as_uint(a);
  unsigned ub = __float_as_uint(b);
  ua = (ua + 0x7FFFu + ((ua >> 16) & 1u)) >> 16;
  ub = (ub + 0x7FFFu + ((ub >> 16) & 1u)) >> 16;
  return ua | (ub << 16);
}

__global__ __launch_bounds__(256) void prep_x(const float4* __restrict__ x4,
                                              uint4* __restrict__ xfrag) {
  const unsigned t = blockIdx.x * 256 + threadIdx.x;  // 524,288 total
  const int l = t & 63;
  const unsigned f = t >> 6;
  const int m16 = f >> 7, k32 = f & 127;
  const int row = m16 * 16 + (l & 15);
  const int c4  = k32 * 8 + (l >> 4) * 2;  // float4 index within row
  const float4* p = x4 + (size_t)row * (KIN / 4) + c4;
  float4 a = p[0], b = p[1];
  uint4 o;
  o.x = pack_bf16(a.x, a.y);
  o.y = pack_bf16(a.z, a.w);
  o.z = pack_bf16(b.x, b.y);
  o.w = pack_bf16(b.z, b.w);
  xfrag[t] = o;
}

// ---- GEMM: no LDS, no barriers. 4 waves/block, wave tile 64x32 (4m x 2n MFMA tiles).
// Grid 512 blocks (2 blocks/CU, 2 waves/SIMD). A-frags: contiguous 1 KB dwordx4 loads
// from Xfrag (L2-resident, XCD-swizzled). B-frags: 1 ushort/lane of bit-bytes, expanded
// in VALU: dword = ((t | t<<15) & 0x10001) * 0x3F80 per bit-pair. Register ping-pong
// prefetch, one kt (BK=64) ahead.
__global__ __launch_bounds__(256, 2) void gemm_bin_kernel(
    const unsigned short* __restrict__ Xf,
    const unsigned short* __restrict__ Bf,
    const float* __restrict__ sf,
    float* __restrict__ C) {
  const int tid  = threadIdx.x;
  const int lane = tid & 63;
  const int wave = tid >> 6;
  const int quad = lane >> 4;
  const int l16  = lane & 15;
  const unsigned bid = blockIdx.x;
  const int by = bid & 7, bx = bid >> 3;   // bid%8 -> XCD: same m-band per XCD (L2 locality)
  const int m0 = by * 128, n0 = bx * 64;
  const int wm = (wave >> 1) * 64, wn = (wave & 1) * 32;
  const int m16b = (m0 + wm) >> 4;  // 4 consecutive m16 tiles
  const int n16b = (n0 + wn) >> 4;  // 2 consecutive n16 tiles

  const uint4* Xf4 = (const uint4*)Xf;

  f32x4_t acc[4][2];
#pragma unroll
  for (int i = 0; i < 4; ++i)
#pragma unroll
    for (int j = 0; j < 2; ++j)
      acc[i][j] = (f32x4_t){0.f, 0.f, 0.f, 0.f};

  auto load_kt = [&](uint4 (&ar)[4][2], unsigned (&br)[2], int kt) {
#pragma unroll
    for (int i = 0; i < 4; ++i)
#pragma unroll
      for (int ks = 0; ks < 2; ++ks)
        ar[i][ks] = Xf4[((size_t)(m16b + i) * 128 + kt * 2 + ks) * 64 + lane];
#pragma unroll
    for (int j = 0; j < 2; ++j)
      br[j] = Bf[((n16b + j) * 64 + kt) * 64 + lane];
  };

  auto compute = [&](uint4 (&ar)[4][2], unsigned (&br)[2]) {
#pragma unroll
    for (int j = 0; j < 2; ++j)
#pragma unroll
      for (int ks = 0; ks < 2; ++ks) {
        unsigned byte = (br[j] >> (ks * 8)) & 0xFFu;
        union { unsigned u[4]; bf16x8_t v; } ex;
#pragma unroll
        for (int p = 0; p < 4; ++p) {
          unsigned tt = (byte >> (2 * p)) & 3u;
          ex.u[p] = ((tt | (tt << 15)) & 0x10001u) * 0x3F80u;
        }
#pragma unroll
        for (int i = 0; i < 4; ++i) {
          union { uint4 q; bf16x8_t v; } av;
          av.q = ar[i][ks];
          acc[i][j] = __builtin_amdgcn_mfma_f32_16x16x32_bf16(av.v, ex.v, acc[i][j], 0, 0, 0);
        }
      }
  };

  uint4 aA[4][2], aB[4][2];
  unsigned bA[2], bB[2];
  load_kt(aA, bA, 0);
  for (int kt = 0; kt < 64; kt += 2) {
    load_kt(aB, bB, kt + 1);
    compute(aA, bA);
    if (kt + 2 < 64) load_kt(aA, bA, kt + 2);
    compute(aB, bB);
  }

  // epilogue: C/D layout col = lane&15, row = quad*4 + reg
#pragma unroll
  for (int j = 0; j < 2; ++j) {
    const int n = n0 + wn + j * 16 + l16;
    const float s = rintf(fmaxf(sf[n], 1.0f));
#pragma unroll
    for (int i = 0; i < 4; ++i) {
      const int mr = m0 + wm + i * 16 + quad * 4;
#pragma unroll
      for (int r = 0; r < 4; ++r)
        C[(size_t)(mr + r) * NOUT + n] = acc[i][j][r] * s;
    }
  }
}

extern "C" void kernel_launch(void* const* d_in, const int* in_sizes, int n_in,
                              void* d_out, int out_size, void* d_ws, size_t ws_size,
                              hipStream_t stream) {
  const float* x  = (const float*)d_in[0];  // [1024][4096]
  const float* w  = (const float*)d_in[1];  // [4096][4096]
  const float* sf = (const float*)d_in[2];  // [4096]
  float* out = (float*)d_out;               // [1024][4096]

  unsigned short*     Bfrag = (unsigned short*)d_ws;                        // 2 MB
  unsigned long long* Wbits = (unsigned long long*)((char*)d_ws + (2u << 20));
  unsigned short*     Xfrag = (unsigned short*)((char*)d_ws + (4u << 20));  // 8 MB

  prep_w<<<1024, 256, 0, stream>>>(w, Wbits);
  prep_w2<<<4096, 256, 0, stream>>>(Wbits, Bfrag);
  prep_x<<<2048, 256, 0, stream>>>((const float4*)x, (uint4*)Xfrag);

  gemm_bin_kernel<<<512, 256, 0, stream>>>(Xfrag, Bfrag, sf, out);
}

// Round 6
// 153.050 us; speedup vs baseline: 1.3430x; 1.0088x over previous
//
#include <hip/hip_runtime.h>

#define M_TOK 1024
#define NOUT  4096
#define KIN   4096

typedef __attribute__((ext_vector_type(8))) short bf16x8_t;
typedef __attribute__((ext_vector_type(4))) float f32x4_t;

// workspace layout:
//   Bfrag  2 MB @ 0        (bit-bytes in MFMA B-frag order)
//   Wbits  2 MB @ 2 MB     (row-major u64 bitmask, intermediate)
//   Xfrag  8 MB @ 4 MB     (bf16 x in MFMA A-frag order)

// ---- prep_w: fp32 -> 1-bit mask via wave ballot (coalesced; known-good) ----
__global__ __launch_bounds__(256) void prep_w(const float* __restrict__ w,
                                              unsigned long long* __restrict__ wbits) {
  const int lane = threadIdx.x & 63;
  const int row  = blockIdx.x * 4 + (threadIdx.x >> 6);
  const float* wr = w + (size_t)row * KIN;
  unsigned long long mine = 0;
#pragma unroll 16
  for (int q = 0; q < 64; ++q) {
    float v = wr[q * 64 + lane];
    unsigned long long m = __ballot(v > 0.f);
    if (lane == q) mine = m;
  }
  wbits[(size_t)row * 64 + lane] = mine;
}

// ---- prep_w2: shuffle bits to B-frag byte order (known-good) ----
__global__ __launch_bounds__(256) void prep_w2(const unsigned long long* __restrict__ wbits,
                                               unsigned short* __restrict__ bfrag) {
  const unsigned t = blockIdx.x * 256 + threadIdx.x;  // 1,048,576 total
  const int l = t & 63, kt = (t >> 6) & 63, n16 = t >> 12;
  const int row = n16 * 16 + (l & 15), quad = l >> 4;
  unsigned long long w64 = wbits[(size_t)row * 64 + kt];
  unsigned b0 = (unsigned)(w64 >> (quad * 8)) & 0xFFu;
  unsigned b1 = (unsigned)(w64 >> (quad * 8 + 32)) & 0xFFu;
  bfrag[t] = (unsigned short)(b0 | (b1 << 8));
}

// ---- prep_x: fp32 -> bf16 RNE in MFMA A-frag order (known-good) ----
__device__ __forceinline__ unsigned pack_bf16(float a, float b) {
  unsigned ua = __float_as_uint(a);
  unsigned ub = __float_as_uint(b);
  ua = (ua + 0x7FFFu + ((ua >> 16) & 1u)) >> 16;
  ub = (ub + 0x7FFFu + ((ub >> 16) & 1u)) >> 16;
  return ua | (ub << 16);
}

__global__ __launch_bounds__(256) void prep_x(const float4* __restrict__ x4,
                                              uint4* __restrict__ xfrag) {
  const unsigned t = blockIdx.x * 256 + threadIdx.x;  // 524,288 total
  const int l = t & 63;
  const unsigned f = t >> 6;
  const int m16 = f >> 7, k32 = f & 127;
  const int row = m16 * 16 + (l & 15);
  const int c4  = k32 * 8 + (l >> 4) * 2;
  const float4* p = x4 + (size_t)row * (KIN / 4) + c4;
  float4 a = p[0], b = p[1];
  uint4 o;
  o.x = pack_bf16(a.x, a.y);
  o.y = pack_bf16(a.z, a.w);
  o.z = pack_bf16(b.x, b.y);
  o.w = pack_bf16(b.z, b.w);
  xfrag[t] = o;
}

// ---- GEMM: no LDS, no barriers. Block tile 64m x 128n; ALL 4 waves share the same
// m-band (identical A-frag streams -> L1 dedup), wn = wave*32. Wave tile 64x32.
// Swizzle: xcd = bid&7 owns m-bands {2*xcd, 2*xcd+1}; that band's A (1 MB) stays
// L2-resident on one XCD while its 32 consumer blocks read it.
__global__ __launch_bounds__(256, 2) void gemm_bin_kernel(
    const unsigned short* __restrict__ Xf,
    const unsigned short* __restrict__ Bf,
    const float* __restrict__ sf,
    float* __restrict__ C) {
  const int tid  = threadIdx.x;
  const int lane = tid & 63;
  const int wave = tid >> 6;
  const int quad = lane >> 4;
  const int l16  = lane & 15;
  const unsigned bid = blockIdx.x;
  const int xcd = bid & 7, idx = bid >> 3;        // idx 0..63
  const int m0 = (xcd * 2 + (idx >> 5)) * 64;     // 16 m-bands, 2 per XCD
  const int n0 = (idx & 31) * 128;                // 32 n-tiles per band
  const int wn = wave * 32;
  const int m16b = m0 >> 4;                       // 4 consecutive m16 tiles (shared)
  const int n16b = (n0 + wn) >> 4;                // 2 consecutive n16 tiles (per wave)

  const uint4* Xf4 = (const uint4*)Xf;

  f32x4_t acc[4][2];
#pragma unroll
  for (int i = 0; i < 4; ++i)
#pragma unroll
    for (int j = 0; j < 2; ++j)
      acc[i][j] = (f32x4_t){0.f, 0.f, 0.f, 0.f};

  auto load_kt = [&](uint4 (&ar)[4][2], unsigned (&br)[2], int kt) {
#pragma unroll
    for (int i = 0; i < 4; ++i)
#pragma unroll
      for (int ks = 0; ks < 2; ++ks)
        ar[i][ks] = Xf4[((size_t)(m16b + i) * 128 + kt * 2 + ks) * 64 + lane];
#pragma unroll
    for (int j = 0; j < 2; ++j)
      br[j] = Bf[((n16b + j) * 64 + kt) * 64 + lane];
  };

  auto compute = [&](uint4 (&ar)[4][2], unsigned (&br)[2]) {
#pragma unroll
    for (int j = 0; j < 2; ++j)
#pragma unroll
      for (int ks = 0; ks < 2; ++ks) {
        unsigned byte = (br[j] >> (ks * 8)) & 0xFFu;
        union { unsigned u[4]; bf16x8_t v; } ex;
#pragma unroll
        for (int p = 0; p < 4; ++p) {
          unsigned tt = (byte >> (2 * p)) & 3u;
          ex.u[p] = ((tt | (tt << 15)) & 0x10001u) * 0x3F80u;
        }
#pragma unroll
        for (int i = 0; i < 4; ++i) {
          union { uint4 q; bf16x8_t v; } av;
          av.q = ar[i][ks];
          acc[i][j] = __builtin_amdgcn_mfma_f32_16x16x32_bf16(av.v, ex.v, acc[i][j], 0, 0, 0);
        }
      }
  };

  uint4 aA[4][2], aB[4][2];
  unsigned bA[2], bB[2];
  load_kt(aA, bA, 0);
  for (int kt = 0; kt < 64; kt += 2) {
    load_kt(aB, bB, kt + 1);
    compute(aA, bA);
    if (kt + 2 < 64) load_kt(aA, bA, kt + 2);
    compute(aB, bB);
  }

  // epilogue: C/D layout col = lane&15, row = quad*4 + reg
#pragma unroll
  for (int j = 0; j < 2; ++j) {
    const int n = n0 + wn + j * 16 + l16;
    const float s = rintf(fmaxf(sf[n], 1.0f));
#pragma unroll
    for (int i = 0; i < 4; ++i) {
      const int mr = m0 + i * 16 + quad * 4;
#pragma unroll
      for (int r = 0; r < 4; ++r)
        C[(size_t)(mr + r) * NOUT + n] = acc[i][j][r] * s;
    }
  }
}

extern "C" void kernel_launch(void* const* d_in, const int* in_sizes, int n_in,
                              void* d_out, int out_size, void* d_ws, size_t ws_size,
                              hipStream_t stream) {
  const float* x  = (const float*)d_in[0];  // [1024][4096]
  const float* w  = (const float*)d_in[1];  // [4096][4096]
  const float* sf = (const float*)d_in[2];  // [4096]
  float* out = (float*)d_out;               // [1024][4096]

  unsigned short*     Bfrag = (unsigned short*)d_ws;                        // 2 MB
  unsigned long long* Wbits = (unsigned long long*)((char*)d_ws + (2u << 20));
  unsigned short*     Xfrag = (unsigned short*)((char*)d_ws + (4u << 20));  // 8 MB

  prep_w<<<1024, 256, 0, stream>>>(w, Wbits);
  prep_w2<<<4096, 256, 0, stream>>>(Wbits, Bfrag);
  prep_x<<<2048, 256, 0, stream>>>((const float4*)x, (uint4*)Xfrag);

  gemm_bin_kernel<<<512, 256, 0, stream>>>(Xfrag, Bfrag, sf, out);
}